// Round 7
// baseline (240.097 us; speedup 1.0000x reference)
//
#include <hip/hip_runtime.h>
#include <math.h>

#define NUM_C 16
#define DIMS 512
#define CHUNKS 64   // row-chunks per class -> 16*64 = 1024 segsum blocks (4/CU)

__device__ inline void atomAddF(float* p, float v) { unsafeAtomicAdd(p, v); }

// ws layout (contiguous zero region first):
//   gcur  @ 0      : 16 ints   (atomic append cursors; final value == counts)
//   gsum  @ 256    : 16*512 f32 (32 KB)
//   gsq   @ 33024  : 16*512 f32 (32 KB)
//   perm  @ 65792  : 16 * N ints (fixed per-class capacity N; ~4 MB)

// ---------------- K1: single-pass scatter (counts+prefix+scatter fused) -----
// Per-block LDS histogram of 1024 ids, one global atomicAdd per class to
// reserve space in class region c*N, then scatter row indices. Block 0 also
// zeroes d_out (stream-ordered before k_pairs reads it).
__global__ __launch_bounds__(256) void k_scatter1p(const int* __restrict__ bids,
                                                   int* __restrict__ gcur,
                                                   int* __restrict__ perm,
                                                   float* __restrict__ out, int n) {
    __shared__ int lh[NUM_C], lb[NUM_C], lc[NUM_C];
    const int tid = threadIdx.x;
    if (blockIdx.x == 0 && tid == 0) out[0] = 0.f;
    if (tid < NUM_C) lh[tid] = 0;
    __syncthreads();
    const int i0 = (blockIdx.x * 256 + tid) * 4;
    int4 c4 = make_int4(0, 0, 0, 0);
    const bool ok = (i0 + 3 < n);
    if (ok) {
        c4 = *reinterpret_cast<const int4*>(bids + i0);
        atomicAdd(&lh[c4.x], 1); atomicAdd(&lh[c4.y], 1);
        atomicAdd(&lh[c4.z], 1); atomicAdd(&lh[c4.w], 1);
    }
    __syncthreads();
    if (tid < NUM_C) {
        lb[tid] = tid * n + atomicAdd(&gcur[tid], lh[tid]);  // region base + old cursor
        lc[tid] = 0;
    }
    __syncthreads();
    if (ok) {
        perm[lb[c4.x] + atomicAdd(&lc[c4.x], 1)] = i0;
        perm[lb[c4.y] + atomicAdd(&lc[c4.y], 1)] = i0 + 1;
        perm[lb[c4.z] + atomicAdd(&lc[c4.z], 1)] = i0 + 2;
        perm[lb[c4.w] + atomicAdd(&lc[c4.w], 1)] = i0 + 3;
    }
}

// ---------------- K2: per-class sum / sumsq, register accumulators ----------
// Block = (class c, chunk). Class uniform per block -> acc in float4 regs.
// 256 threads: half = tid>>7 takes every 2nd row; 128 threads x float4 = full
// 2KB row, perfectly coalesced. No LDS in hot loop. 1024 blocks = 4/CU.
__global__ __launch_bounds__(256) void k_segsum(const float* __restrict__ hidden,
                                                const int* __restrict__ perm,
                                                const int* __restrict__ gcur,
                                                float* __restrict__ gsum,
                                                float* __restrict__ gsq, int n) {
    const int tid = threadIdx.x;
    const int c = blockIdx.x & (NUM_C - 1);
    const int chunk = blockIdx.x >> 4;
    const int cnt = gcur[c];
    const int base = c * n;
    const int len = (cnt + CHUNKS - 1) / CHUNKS;
    const int lo = chunk * len;
    const int hi = min(lo + len, cnt);
    const int half = tid >> 7, ht = tid & 127;

    float4 s = {0.f, 0.f, 0.f, 0.f}, q = {0.f, 0.f, 0.f, 0.f};
#define LOADROW(r) (*(reinterpret_cast<const float4*>(hidden + (size_t)(r) * DIMS) + ht))
#define ACC(v) { s.x += (v).x; s.y += (v).y; s.z += (v).z; s.w += (v).w; \
                 q.x += (v).x*(v).x; q.y += (v).y*(v).y; q.z += (v).z*(v).z; q.w += (v).w*(v).w; }
    int k = lo + half;
    for (; k + 6 < hi; k += 8) {
        const int r0 = perm[base + k],     r1 = perm[base + k + 2];
        const int r2 = perm[base + k + 4], r3 = perm[base + k + 6];
        const float4 v0 = LOADROW(r0), v1 = LOADROW(r1);
        const float4 v2 = LOADROW(r2), v3 = LOADROW(r3);
        ACC(v0); ACC(v1); ACC(v2); ACC(v3);
    }
    for (; k < hi; k += 2) {
        const int r0 = perm[base + k];
        const float4 v0 = LOADROW(r0);
        ACC(v0);
    }
#undef LOADROW
#undef ACC

    // combine the two halves through LDS, then native-f32 atomic flush
    __shared__ float red[128 * 8];
    if (half == 1) {
        float* p = &red[ht * 8];
        p[0] = s.x; p[1] = s.y; p[2] = s.z; p[3] = s.w;
        p[4] = q.x; p[5] = q.y; p[6] = q.z; p[7] = q.w;
    }
    __syncthreads();
    if (half == 0) {
        const float* p = &red[ht * 8];
        s.x += p[0]; s.y += p[1]; s.z += p[2]; s.w += p[3];
        q.x += p[4]; q.y += p[5]; q.z += p[6]; q.w += p[7];
        float* gs = gsum + c * DIMS + 4 * ht;
        float* gq = gsq  + c * DIMS + 4 * ht;
        atomAddF(gs + 0, s.x); atomAddF(gs + 1, s.y);
        atomAddF(gs + 2, s.z); atomAddF(gs + 3, s.w);
        atomAddF(gq + 0, q.x); atomAddF(gq + 1, q.y);
        atomAddF(gq + 2, q.z); atomAddF(gq + 3, q.w);
    }
}

// ---------------- K3: pairs — inline means/withins, sort, Simpson betainc ---
// means/withins folded in: m = s/n, w = max(q - s*m, 0).
// I_x(1/2,b) = (2/B(1/2,b)) * Int_0^sqrt(x) (1-u^2)^(b-1) du
// Composite Simpson (256 intervals), f32, split over 8 lanes per x-value.
// Monotone in x -> top-d of betainc == betainc of top-d x (sort x only).
__global__ __launch_bounds__(512) void k_pairs(const float* __restrict__ gsum,
                                               const float* __restrict__ gsq,
                                               const int* __restrict__ gcur,
                                               const int* __restrict__ dptr,
                                               float* __restrict__ out) {
    __shared__ float xs[DIMS];
    __shared__ float wsum[8];
    const int tid = threadIdx.x;

    int p = blockIdx.x, i = 0, rem = p;
    while (rem >= NUM_C - 1 - i) { rem -= NUM_C - 1 - i; ++i; }
    const int j = i + 1 + rem;

    const float ni = (float)gcur[i], nj = (float)gcur[j];
    const float pc = ni + nj;

    {
        const float si = gsum[i * DIMS + tid];
        const float sj = gsum[j * DIMS + tid];
        const float mi = si / ni, mj = sj / nj;
        float wi = gsq[i * DIMS + tid] - si * mi;  wi = wi > 0.f ? wi : 0.f;
        float wj = gsq[j * DIMS + tid] - sj * mj;  wj = wj > 0.f ? wj : 0.f;
        const float hd = (mi - mj) * 0.5f;
        const float between = hd * hd * pc;
        const float within = wi + wj;
        float x = between / (between + within);
        if (!(x >= 1e-37f)) x = 1e-37f;          // also catches NaN
        const float XM = 1.0f - 1e-5f;
        if (x > XM) x = XM;
        xs[tid] = x;
    }

    // bitonic sort descending (f32)
    for (int kk = 2; kk <= DIMS; kk <<= 1) {
        for (int jj = kk >> 1; jj > 0; jj >>= 1) {
            __syncthreads();
            const int ixj = tid ^ jj;
            if (ixj > tid) {
                const float va = xs[tid], vb = xs[ixj];
                const bool sw = ((tid & kk) == 0) ? (va < vb) : (va > vb);
                if (sw) { xs[tid] = vb; xs[ixj] = va; }
            }
        }
    }
    __syncthreads();

    const int d = *dptr;
    float d2 = pc - 2.0f;
    if (d2 == 0.0f) d2 = 1e-5f;
    const float b = d2 * 0.5f;
    const float bm1 = b - 1.0f;
    const float invb = 1.0f / b;
    // ln(2/B) = ln2 - [0.5*(ln pi - ln b) + log1p(1/(8b) + 1/(128 b^2))]
    const float ln2overB = 0.69314718f
        - (0.5f * (1.14472989f - logf(b)) + log1pf(invb * (0.125f + 0.0078125f * invb)));

    const int sub = tid & 7;
    const int rounds = (d + 63) >> 6;            // q-groups of 64 per pass
    float part = 0.f;
    for (int r = 0; r < rounds; ++r) {
        const int q = (tid >> 3) + (r << 6);
        const bool act = (q < d);
        const float x = xs[act ? q : 0];
        const float rt = sqrtf(x);
        const float h = rt * (1.0f / 256.0f);
        float acc = 0.f;
        for (int k = sub; k <= 256; k += 8) {
            const float sv = (float)k * h;
            const float w = (k == 0 || k == 256) ? 1.f : ((k & 1) ? 4.f : 2.f);
            acc += w * __expf(bm1 * log1pf(-sv * sv));
        }
        acc += __shfl_down(acc, 4, 64);
        acc += __shfl_down(acc, 2, 64);
        acc += __shfl_down(acc, 1, 64);
        if (sub == 0 && act) {
            float li = logf(acc * h * (1.0f / 3.0f)) + ln2overB;
            part += (li < 0.f) ? li : 0.f;       // betainc <= 1
        }
    }
    for (int off = 32; off > 0; off >>= 1) part += __shfl_down(part, off, 64);
    if ((tid & 63) == 0) wsum[tid >> 6] = part;
    __syncthreads();
    if (tid == 0) {
        float t = 0.f;
        for (int w = 0; w < 8; ++w) t += wsum[w];
        atomAddF(out, -t);
    }
}

// ---------------- launch: 4 graph nodes total ----------------
extern "C" void kernel_launch(void* const* d_in, const int* in_sizes, int n_in,
                              void* d_out, int out_size, void* d_ws, size_t ws_size,
                              hipStream_t stream) {
    const float* hidden = (const float*)d_in[0];
    const int* bids = (const int*)d_in[1];
    const int* dptr = (const int*)d_in[2];
    float* out = (float*)d_out;
    const int N = in_sizes[1];

    char* ws = (char*)d_ws;
    int*   gcur = (int*)(ws + 0);        // 16 ints (cursor == counts when done)
    float* gsum = (float*)(ws + 256);    // 16*512 f32
    float* gsq  = (float*)(ws + 33024);  // 16*512 f32
    int*   perm = (int*)(ws + 65792);    // 16 * N ints (per-class capacity N)

    hipMemsetAsync(d_ws, 0, 65792, stream);                 // gcur + gsum + gsq

    const int nb = (N + 1023) / 1024;                       // 4 ids/thread
    k_scatter1p<<<nb, 256, 0, stream>>>(bids, gcur, perm, out, N);
    k_segsum  <<<NUM_C * CHUNKS, 256, 0, stream>>>(hidden, perm, gcur, gsum, gsq, N);
    k_pairs   <<<NUM_C * (NUM_C - 1) / 2, 512, 0, stream>>>(gsum, gsq, gcur, dptr, out);
}